// Round 4
// baseline (2174.342 us; speedup 1.0000x reference)
//
#include <hip/hip_runtime.h>
#include <hip/hip_bf16.h>
#include <math.h>

// monotone encoding of float for unsigned atomicMax (0 is identity)
__device__ __forceinline__ unsigned f2mono(float f){
    unsigned u = __float_as_uint(f);
    return (u & 0x80000000u) ? ~u : (u | 0x80000000u);
}
__device__ __forceinline__ float mono2f(unsigned u){
    return (u & 0x80000000u) ? __uint_as_float(u & 0x7fffffffu) : __uint_as_float(~u);
}

__global__ void k_zero(float* __restrict__ p, long long n)
{
    for (long long i = (long long)blockIdx.x*blockDim.x + threadIdx.x; i < n;
         i += (long long)gridDim.x*blockDim.x)
        p[i] = 0.f;
}

// h = x @ in_w + in_b   (one block per node, 128 threads, grid-stride over nodes)
__global__ void k_in_proj(const float* __restrict__ x, const float* __restrict__ w,
                          const float* __restrict__ b, float* __restrict__ h,
                          int n_nodes)
{
    __shared__ float row[128];
    int tid = threadIdx.x;
    for (int n = blockIdx.x; n < n_nodes; n += gridDim.x) {
        __syncthreads();
        row[tid] = x[(size_t)n*128 + tid];
        __syncthreads();
        float acc = b[tid];
        #pragma unroll 8
        for (int k = 0; k < 128; ++k) acc += row[k] * w[k*128 + tid];
        h[(size_t)n*128 + tid] = acc;
    }
}

// kqv = h @ kqv_w[l] + kqv_b[l]; then k_rel/v_rel per edge type, fused.
__global__ void k_kqv_rel(const float* __restrict__ h, const float* __restrict__ kqv_w,
                          const float* __restrict__ kqv_b, const float* __restrict__ krel_w,
                          const float* __restrict__ vrel_w, float* __restrict__ q,
                          float* __restrict__ krel, float* __restrict__ vrel,
                          int l, int n_nodes)
{
    __shared__ float hrow[128], klds[128], vlds[128];
    int tid = threadIdx.x;
    for (int n = blockIdx.x; n < n_nodes; n += gridDim.x) {
        __syncthreads();
        hrow[tid] = h[(size_t)n*128 + tid];
        __syncthreads();
        const float* wl = kqv_w + (size_t)l*128*384;
        const float* bl = kqv_b + l*384;
        float acck = bl[tid], accq = bl[128+tid], accv = bl[256+tid];
        for (int k = 0; k < 128; ++k) {
            float hv = hrow[k];
            const float* wr = wl + k*384;
            acck += hv * wr[tid];
            accq += hv * wr[128+tid];
            accv += hv * wr[256+tid];
        }
        q[(size_t)n*128 + tid] = accq;
        klds[tid] = acck; vlds[tid] = accv;
        __syncthreads();
        int hd = tid >> 4, f = tid & 15;
        #pragma unroll
        for (int t = 0; t < 2; ++t) {
            const float* wk = krel_w + (((size_t)(l*2 + t)*8 + hd)*16)*16;
            const float* wv = vrel_w + (((size_t)(l*2 + t)*8 + hd)*16)*16;
            float ak = 0.f, av = 0.f;
            #pragma unroll
            for (int d = 0; d < 16; ++d) {
                ak += klds[hd*16 + d] * wk[d*16 + f];
                av += vlds[hd*16 + d] * wv[d*16 + f];
            }
            krel[((size_t)t*n_nodes + n)*128 + tid] = ak;
            vrel[((size_t)t*n_nodes + n)*128 + tid] = av;
        }
    }
}

// per (edge, head): alpha = (q[dst]·k_rel[src]) * p * scale; atomicMax segment max
__global__ void k_alpha(const int* __restrict__ ef, const int* __restrict__ er,
                        const float* __restrict__ q, const float* __restrict__ krel,
                        const float* __restrict__ p_rel, float* __restrict__ alpha,
                        unsigned* __restrict__ m, int l, int n_nodes, int Ef, int Er)
{
    int Etot = Ef + Er;
    for (int idx = blockIdx.x*blockDim.x + threadIdx.x; idx < Etot*8;
         idx += gridDim.x*blockDim.x) {
        int e = idx >> 3, hd = idx & 7;
        int t, src, dst;
        if (e < Ef) { t = 0; src = ef[e]; dst = ef[Ef + e]; }
        else        { t = 1; int e2 = e - Ef; src = er[e2]; dst = er[Er + e2]; }
        const float* qp = q + (size_t)dst*128 + hd*16;
        const float* kp = krel + ((size_t)t*n_nodes + src)*128 + hd*16;
        float acc = 0.f;
        #pragma unroll
        for (int d = 0; d < 16; ++d) acc += qp[d]*kp[d];
        float p = p_rel[(l*2 + t)*8 + hd];
        float a = acc * p * 0.25f;   // scale = 1/sqrt(16)
        alpha[(size_t)e*8 + hd] = a;
        atomicMax(m + (size_t)dst*8 + hd, f2mono(a));
    }
}

// per (edge, feature): w = exp(alpha - m); scatter numerator + denominator
__global__ void k_scatter(const int* __restrict__ ef, const int* __restrict__ er,
                          const float* __restrict__ vrel, const float* __restrict__ alpha,
                          const unsigned* __restrict__ m, float* __restrict__ denom,
                          float* __restrict__ agg, int n_nodes, int Ef, int Er)
{
    long long tot = (long long)(Ef + Er)*128;
    for (long long idx = (long long)blockIdx.x*blockDim.x + threadIdx.x; idx < tot;
         idx += (long long)gridDim.x*blockDim.x) {
        int e = (int)(idx >> 7), r = (int)(idx & 127);
        int hd = r >> 4;
        int t, src, dst;
        if (e < Ef) { t = 0; src = ef[e]; dst = ef[Ef + e]; }
        else        { t = 1; int e2 = e - Ef; src = er[e2]; dst = er[Er + e2]; }
        float a = alpha[(size_t)e*8 + hd];
        float mv = mono2f(m[(size_t)dst*8 + hd]);
        float w = expf(a - mv);
        float val = w * vrel[((size_t)t*n_nodes + src)*128 + r];
        atomicAdd(agg + (size_t)dst*128 + r, val);
        if ((r & 15) == 0) atomicAdd(denom + (size_t)dst*8 + hd, w);
    }
}

// agg = gelu(agg / (denom + 1e-16))
__global__ void k_norm_gelu(const float* __restrict__ denom, float* __restrict__ agg,
                            int n_nodes)
{
    int tot = n_nodes*128;
    for (int idx = blockIdx.x*blockDim.x + threadIdx.x; idx < tot;
         idx += gridDim.x*blockDim.x) {
        int n = idx >> 7, hd = (idx >> 4) & 7;
        float x = agg[idx] / (denom[n*8 + hd] + 1e-16f);
        agg[idx] = 0.5f * x * (1.f + erff(x * 0.70710678118654752f));
    }
}

// a = ag @ out_w[l] + out_b[l]; h = relu(g*a + (1-g)*h)
__global__ void k_out_proj(const float* __restrict__ ag, const float* __restrict__ out_w,
                           const float* __restrict__ out_b, const float* __restrict__ skip,
                           float* __restrict__ h, int l, int n_nodes)
{
    __shared__ float row[128];
    int tid = threadIdx.x;
    for (int n = blockIdx.x; n < n_nodes; n += gridDim.x) {
        __syncthreads();
        row[tid] = ag[(size_t)n*128 + tid];
        __syncthreads();
        const float* wl = out_w + (size_t)l*128*128;
        float acc = out_b[l*128 + tid];
        #pragma unroll 8
        for (int k = 0; k < 128; ++k) acc += row[k] * wl[k*128 + tid];
        float g = 1.f/(1.f + expf(-skip[l]));
        size_t i = (size_t)n*128 + tid;
        float hv = g*acc + (1.f - g)*h[i];
        h[i] = fmaxf(hv, 0.f);
    }
}

// logits = h @ head_w + head_b  (block per node, LDS tree reduce)
__global__ void k_head(const float* __restrict__ h, const float* __restrict__ head_w,
                       const float* __restrict__ head_b, float* __restrict__ out,
                       int n_nodes)
{
    __shared__ float s0[128], s1[128];
    int tid = threadIdx.x;
    for (int n = blockIdx.x; n < n_nodes; n += gridDim.x) {
        __syncthreads();
        float hv = h[(size_t)n*128 + tid];
        s0[tid] = hv * head_w[tid*2];
        s1[tid] = hv * head_w[tid*2 + 1];
        __syncthreads();
        for (int s = 64; s > 0; s >>= 1) {
            if (tid < s) { s0[tid] += s0[tid + s]; s1[tid] += s1[tid + s]; }
            __syncthreads();
        }
        if (tid == 0) {
            out[n*2]     = s0[0] + head_b[0];
            out[n*2 + 1] = s1[0] + head_b[1];
        }
    }
}

extern "C" void kernel_launch(void* const* d_in, const int* in_sizes, int n_in,
                              void* d_out, int out_size, void* d_ws, size_t ws_size,
                              hipStream_t stream)
{
    const float* x      = (const float*)d_in[0];
    const int*   ef     = (const int*)d_in[1];
    const int*   er     = (const int*)d_in[2];
    const float* in_w   = (const float*)d_in[3];
    const float* in_b   = (const float*)d_in[4];
    const float* kqv_w  = (const float*)d_in[5];
    const float* kqv_b  = (const float*)d_in[6];
    const float* krel_w = (const float*)d_in[7];
    const float* vrel_w = (const float*)d_in[8];
    const float* p_rel  = (const float*)d_in[9];
    const float* out_w  = (const float*)d_in[10];
    const float* out_b  = (const float*)d_in[11];
    const float* skip   = (const float*)d_in[12];
    const float* head_w = (const float*)d_in[13];
    const float* head_b = (const float*)d_in[14];
    float* out = (float*)d_out;

    int n_nodes = in_sizes[0] / 128;
    int Ef = in_sizes[1] / 2, Er = in_sizes[2] / 2;
    int Etot = Ef + Er;

    // workspace layout (all f32). agg aliases q (q dead after k_alpha).
    float* p = (float*)d_ws;
    float* h     = p; p += (size_t)n_nodes*128;
    float* q     = p; p += (size_t)n_nodes*128;
    float* agg   = q;                               // alias
    float* krel  = p; p += (size_t)2*n_nodes*128;
    float* vrel  = p; p += (size_t)2*n_nodes*128;
    float* alpha = p; p += (size_t)Etot*8;
    unsigned* m  = (unsigned*)p; p += (size_t)n_nodes*8;
    float* denom = p; p += (size_t)n_nodes*8;

    const int GB = 2048;   // grid-stride block count for big launches

    k_in_proj<<<GB, 128, 0, stream>>>(x, in_w, in_b, h, n_nodes);

    for (int l = 0; l < 2; ++l) {
        k_kqv_rel<<<GB, 128, 0, stream>>>(h, kqv_w, kqv_b, krel_w, vrel_w,
                                          q, krel, vrel, l, n_nodes);
        // m and denom are adjacent in layout: zero both in one grid-stride pass
        k_zero<<<256, 256, 0, stream>>>((float*)m, (long long)n_nodes*16);
        k_alpha<<<GB, 256, 0, stream>>>(ef, er, q, krel, p_rel, alpha, m,
                                        l, n_nodes, Ef, Er);
        // q is dead now; zero agg (= q) for the scatter accumulation
        k_zero<<<GB, 256, 0, stream>>>(agg, (long long)n_nodes*128);
        k_scatter<<<8192, 256, 0, stream>>>(ef, er, vrel, alpha, m, denom, agg,
                                            n_nodes, Ef, Er);
        k_norm_gelu<<<GB, 256, 0, stream>>>(denom, agg, n_nodes);
        k_out_proj<<<GB, 128, 0, stream>>>(agg, out_w, out_b, skip, h, l, n_nodes);
    }
    k_head<<<GB, 128, 0, stream>>>(h, head_w, head_b, out, n_nodes);
}

// Round 5
// 1056.195 us; speedup vs baseline: 2.0587x; 2.0587x over previous
//
#include <hip/hip_runtime.h>
#include <math.h>

// ---------------- CSR build ----------------
__global__ void k_zero_i(int* __restrict__ p, int n)
{
    for (int i = blockIdx.x*blockDim.x + threadIdx.x; i < n; i += gridDim.x*blockDim.x)
        p[i] = 0;
}

__global__ void k_count(const int* __restrict__ ef, const int* __restrict__ er,
                        int* __restrict__ deg, int Ef, int Er)
{
    int Etot = Ef + Er;
    for (int e = blockIdx.x*blockDim.x + threadIdx.x; e < Etot; e += gridDim.x*blockDim.x) {
        int dst = (e < Ef) ? ef[Ef + e] : er[Er + (e - Ef)];
        atomicAdd(&deg[dst], 1);
    }
}

__global__ void k_chunk_sums(const int* __restrict__ deg, int* __restrict__ csum, int n)
{
    __shared__ int s[256];
    int t = threadIdx.x, i = blockIdx.x*256 + t;
    s[t] = (i < n) ? deg[i] : 0;
    __syncthreads();
    for (int off = 128; off > 0; off >>= 1) {
        if (t < off) s[t] += s[t + off];
        __syncthreads();
    }
    if (t == 0) csum[blockIdx.x] = s[0];
}

// exclusive scan of csum in place (nch <= 1024), single block of 1024
__global__ void k_scan_chunks(int* __restrict__ csum, int nch)
{
    __shared__ int s[1024];
    int t = threadIdx.x;
    int v = (t < nch) ? csum[t] : 0;
    s[t] = v; __syncthreads();
    for (int off = 1; off < 1024; off <<= 1) {
        int u = (t >= off) ? s[t - off] : 0;
        __syncthreads();
        s[t] += u;
        __syncthreads();
    }
    if (t < nch) csum[t] = s[t] - v;
}

// row_start[i] (i<=n) + cursor init
__global__ void k_rowstart(const int* __restrict__ deg, const int* __restrict__ csum,
                           int* __restrict__ row_start, int* __restrict__ cursor, int n)
{
    __shared__ int s[256];
    int t = threadIdx.x, i = blockIdx.x*256 + t;
    int d = (i < n) ? deg[i] : 0;
    s[t] = d; __syncthreads();
    for (int off = 1; off < 256; off <<= 1) {
        int u = (t >= off) ? s[t - off] : 0;
        __syncthreads();
        s[t] += u;
        __syncthreads();
    }
    if (i <= n) {
        int rs = csum[blockIdx.x] + s[t] - d;   // exclusive
        row_start[i] = rs;
        cursor[i] = rs;
    }
}

__global__ void k_fill(const int* __restrict__ ef, const int* __restrict__ er,
                       int* __restrict__ cursor, unsigned* __restrict__ srcs,
                       int Ef, int Er)
{
    int Etot = Ef + Er;
    for (int e = blockIdx.x*blockDim.x + threadIdx.x; e < Etot; e += gridDim.x*blockDim.x) {
        int src, dst; unsigned tbit;
        if (e < Ef) { src = ef[e]; dst = ef[Ef + e]; tbit = 0u; }
        else { int e2 = e - Ef; src = er[e2]; dst = er[Er + e2]; tbit = 0x80000000u; }
        int pos = atomicAdd(&cursor[dst], 1);
        srcs[pos] = (unsigned)src | tbit;
    }
}

// ---------------- node GEMMs (16 nodes / block) ----------------
// in_proj: 64 threads, 2 cols/thread
__global__ __launch_bounds__(64) void k_in_proj_t(
    const float* __restrict__ x, const float* __restrict__ w,
    const float* __restrict__ b, float* __restrict__ h, int n_nodes)
{
    __shared__ float xt[16][128];
    int t = threadIdx.x, base = blockIdx.x*16;
    int lim = n_nodes - base; if (lim > 16) lim = 16;
    for (int r = 0; r < lim; ++r) {
        xt[r][t]      = x[(size_t)(base+r)*128 + t];
        xt[r][t + 64] = x[(size_t)(base+r)*128 + t + 64];
    }
    __syncthreads();
    float acc0[16], acc1[16];
    float b0 = b[t], b1 = b[t + 64];
    #pragma unroll
    for (int r = 0; r < 16; ++r) { acc0[r] = b0; acc1[r] = b1; }
    for (int k4 = 0; k4 < 32; ++k4) {
        int k = k4*4;
        float w00 = w[(k+0)*128 + t], w01 = w[(k+0)*128 + t + 64];
        float w10 = w[(k+1)*128 + t], w11 = w[(k+1)*128 + t + 64];
        float w20 = w[(k+2)*128 + t], w21 = w[(k+2)*128 + t + 64];
        float w30 = w[(k+3)*128 + t], w31 = w[(k+3)*128 + t + 64];
        #pragma unroll
        for (int r = 0; r < 16; ++r) {
            float4 hv = *(const float4*)&xt[r][k];
            acc0[r] += hv.x*w00 + hv.y*w10 + hv.z*w20 + hv.w*w30;
            acc1[r] += hv.x*w01 + hv.y*w11 + hv.z*w21 + hv.w*w31;
        }
    }
    for (int r = 0; r < lim; ++r) {
        h[(size_t)(base+r)*128 + t]      = acc0[r];
        h[(size_t)(base+r)*128 + t + 64] = acc1[r];
    }
}

// kqv + rel transforms: 128 threads, 3 cols/thread (k,q,v)
__global__ __launch_bounds__(128) void k_kqv_rel_t(
    const float* __restrict__ h, const float* __restrict__ kqv_w,
    const float* __restrict__ kqv_b, const float* __restrict__ krel_w,
    const float* __restrict__ vrel_w, float* __restrict__ qa,
    float* __restrict__ krel, float* __restrict__ vrel, int l, int n_nodes)
{
    __shared__ float ht[16][128];
    __shared__ float kl[16][128];
    __shared__ float vl[16][128];
    int t = threadIdx.x, base = blockIdx.x*16;
    int lim = n_nodes - base; if (lim > 16) lim = 16;
    for (int r = 0; r < lim; ++r) ht[r][t] = h[(size_t)(base+r)*128 + t];
    __syncthreads();
    const float* wl = kqv_w + (size_t)l*128*384;
    const float* bl = kqv_b + (size_t)l*384;
    float acck[16], accq[16], accv[16];
    float bk = bl[t], bq = bl[128 + t], bv = bl[256 + t];
    #pragma unroll
    for (int r = 0; r < 16; ++r) { acck[r] = bk; accq[r] = bq; accv[r] = bv; }
    for (int k4 = 0; k4 < 32; ++k4) {
        int k = k4*4;
        float wk0 = wl[(k+0)*384 + t], wq0 = wl[(k+0)*384 + 128 + t], wv0 = wl[(k+0)*384 + 256 + t];
        float wk1 = wl[(k+1)*384 + t], wq1 = wl[(k+1)*384 + 128 + t], wv1 = wl[(k+1)*384 + 256 + t];
        float wk2 = wl[(k+2)*384 + t], wq2 = wl[(k+2)*384 + 128 + t], wv2 = wl[(k+2)*384 + 256 + t];
        float wk3 = wl[(k+3)*384 + t], wq3 = wl[(k+3)*384 + 128 + t], wv3 = wl[(k+3)*384 + 256 + t];
        #pragma unroll
        for (int r = 0; r < 16; ++r) {
            float4 hv = *(const float4*)&ht[r][k];
            acck[r] += hv.x*wk0 + hv.y*wk1 + hv.z*wk2 + hv.w*wk3;
            accq[r] += hv.x*wq0 + hv.y*wq1 + hv.z*wq2 + hv.w*wq3;
            accv[r] += hv.x*wv0 + hv.y*wv1 + hv.z*wv2 + hv.w*wv3;
        }
    }
    for (int r = 0; r < lim; ++r) qa[(size_t)(base+r)*128 + t] = accq[r];
    #pragma unroll
    for (int r = 0; r < 16; ++r) { kl[r][t] = acck[r]; vl[r][t] = accv[r]; }
    __syncthreads();
    int hd = t >> 4, f = t & 15;
    for (int tt = 0; tt < 2; ++tt) {
        const float* wk = krel_w + (((size_t)(l*2 + tt)*8 + hd)*16)*16;
        const float* wv = vrel_w + (((size_t)(l*2 + tt)*8 + hd)*16)*16;
        float ak[16], av[16];
        #pragma unroll
        for (int r = 0; r < 16; ++r) { ak[r] = 0.f; av[r] = 0.f; }
        for (int d = 0; d < 16; ++d) {
            float a = wk[d*16 + f], b = wv[d*16 + f];
            #pragma unroll
            for (int r = 0; r < 16; ++r) {
                ak[r] += kl[r][hd*16 + d]*a;
                av[r] += vl[r][hd*16 + d]*b;
            }
        }
        for (int r = 0; r < lim; ++r) {
            krel[((size_t)tt*n_nodes + base + r)*128 + t] = ak[r];
            vrel[((size_t)tt*n_nodes + base + r)*128 + t] = av[r];
        }
    }
}

// fused gather attention: one block (128 thr) per dst node, online softmax, gelu epilogue.
// qa holds q on entry, gelu(agg/denom) on exit (block touches only its own 128-float row).
__global__ __launch_bounds__(128) void k_attn(
    const unsigned* __restrict__ srcs, const int* __restrict__ row_start,
    const float* __restrict__ krel, const float* __restrict__ vrel,
    const float* __restrict__ p_rel, float* __restrict__ qa, int l, int n_nodes)
{
    int n = blockIdx.x;
    if (n >= n_nodes) return;
    int t = threadIdx.x, hd = t >> 4;
    float qv = qa[(size_t)n*128 + t];
    float p0 = p_rel[(2*l)*8 + hd] * 0.25f;
    float p1 = p_rel[(2*l + 1)*8 + hd] * 0.25f;
    int s = row_start[n], e = row_start[n + 1];
    float m = -INFINITY, lsum = 0.f, acc = 0.f;
    for (int pos = s; pos < e; ++pos) {
        unsigned sv = srcs[pos];
        int src = (int)(sv & 0x7fffffffu);
        int tt = (int)(sv >> 31);
        size_t bofs = ((size_t)tt*n_nodes + src)*128 + t;
        float kv = krel[bofs];
        float vv = vrel[bofs];
        float d = qv*kv;
        d += __shfl_xor(d, 1); d += __shfl_xor(d, 2);
        d += __shfl_xor(d, 4); d += __shfl_xor(d, 8);
        float a = d * (tt ? p1 : p0);
        float mn = fmaxf(m, a);
        float sc = expf(m - mn);
        float w  = expf(a - mn);
        lsum = lsum*sc + w;
        acc  = acc*sc + w*vv;
        m = mn;
    }
    float xo = acc / (lsum + 1e-16f);
    qa[(size_t)n*128 + t] = 0.5f*xo*(1.f + erff(xo*0.70710678118654752f));
}

// out_proj + skip + relu: 64 threads, 2 cols/thread
__global__ __launch_bounds__(64) void k_out_proj_t(
    const float* __restrict__ ag, const float* __restrict__ out_w,
    const float* __restrict__ out_b, const float* __restrict__ skip,
    float* __restrict__ h, int l, int n_nodes)
{
    __shared__ float xt[16][128];
    int t = threadIdx.x, base = blockIdx.x*16;
    int lim = n_nodes - base; if (lim > 16) lim = 16;
    for (int r = 0; r < lim; ++r) {
        xt[r][t]      = ag[(size_t)(base+r)*128 + t];
        xt[r][t + 64] = ag[(size_t)(base+r)*128 + t + 64];
    }
    __syncthreads();
    const float* wl = out_w + (size_t)l*128*128;
    float acc0[16], acc1[16];
    float b0 = out_b[l*128 + t], b1 = out_b[l*128 + t + 64];
    #pragma unroll
    for (int r = 0; r < 16; ++r) { acc0[r] = b0; acc1[r] = b1; }
    for (int k4 = 0; k4 < 32; ++k4) {
        int k = k4*4;
        float w00 = wl[(k+0)*128 + t], w01 = wl[(k+0)*128 + t + 64];
        float w10 = wl[(k+1)*128 + t], w11 = wl[(k+1)*128 + t + 64];
        float w20 = wl[(k+2)*128 + t], w21 = wl[(k+2)*128 + t + 64];
        float w30 = wl[(k+3)*128 + t], w31 = wl[(k+3)*128 + t + 64];
        #pragma unroll
        for (int r = 0; r < 16; ++r) {
            float4 hv = *(const float4*)&xt[r][k];
            acc0[r] += hv.x*w00 + hv.y*w10 + hv.z*w20 + hv.w*w30;
            acc1[r] += hv.x*w01 + hv.y*w11 + hv.z*w21 + hv.w*w31;
        }
    }
    float g = 1.f/(1.f + expf(-skip[l]));
    for (int r = 0; r < lim; ++r) {
        size_t i0 = (size_t)(base+r)*128 + t;
        size_t i1 = i0 + 64;
        float h0 = g*acc0[r] + (1.f - g)*h[i0];
        float h1 = g*acc1[r] + (1.f - g)*h[i1];
        h[i0] = fmaxf(h0, 0.f);
        h[i1] = fmaxf(h1, 0.f);
    }
}

// head: one wave per node, shuffle reduce
__global__ __launch_bounds__(64) void k_head(
    const float* __restrict__ h, const float* __restrict__ hw,
    const float* __restrict__ hb, float* __restrict__ out, int n_nodes)
{
    int n = blockIdx.x;
    if (n >= n_nodes) return;
    int t = threadIdx.x;
    float h0 = h[(size_t)n*128 + t], h1 = h[(size_t)n*128 + 64 + t];
    float c0 = h0*hw[t*2]     + h1*hw[(t+64)*2];
    float c1 = h0*hw[t*2 + 1] + h1*hw[(t+64)*2 + 1];
    for (int off = 32; off > 0; off >>= 1) {
        c0 += __shfl_down(c0, off);
        c1 += __shfl_down(c1, off);
    }
    if (t == 0) {
        out[n*2]     = c0 + hb[0];
        out[n*2 + 1] = c1 + hb[1];
    }
}

extern "C" void kernel_launch(void* const* d_in, const int* in_sizes, int n_in,
                              void* d_out, int out_size, void* d_ws, size_t ws_size,
                              hipStream_t stream)
{
    const float* x      = (const float*)d_in[0];
    const int*   ef     = (const int*)d_in[1];
    const int*   er     = (const int*)d_in[2];
    const float* in_w   = (const float*)d_in[3];
    const float* in_b   = (const float*)d_in[4];
    const float* kqv_w  = (const float*)d_in[5];
    const float* kqv_b  = (const float*)d_in[6];
    const float* krel_w = (const float*)d_in[7];
    const float* vrel_w = (const float*)d_in[8];
    const float* p_rel  = (const float*)d_in[9];
    const float* out_w  = (const float*)d_in[10];
    const float* out_b  = (const float*)d_in[11];
    const float* skip   = (const float*)d_in[12];
    const float* head_w = (const float*)d_in[13];
    const float* head_b = (const float*)d_in[14];
    float* out = (float*)d_out;

    int n_nodes = in_sizes[0] / 128;
    int Ef = in_sizes[1] / 2, Er = in_sizes[2] / 2;
    int Etot = Ef + Er;
    int nch = (n_nodes + 255)/256;          // chunks for scan (196 for N=50k)

    // workspace (all within ~158 MB; q and agg share one buffer)
    float* p = (float*)d_ws;
    float* h    = p; p += (size_t)n_nodes*128;
    float* qa   = p; p += (size_t)n_nodes*128;
    float* krel = p; p += (size_t)2*n_nodes*128;
    float* vrel = p; p += (size_t)2*n_nodes*128;
    int* deg       = (int*)p;           p += n_nodes;
    int* csum      = (int*)p;           p += 1024;
    int* row_start = (int*)p;           p += n_nodes + 1;
    int* cursor    = (int*)p;           p += n_nodes + 1;
    unsigned* srcs = (unsigned*)p;      p += Etot;

    int nb16 = (n_nodes + 15)/16;

    // ---- CSR build (layer-independent) ----
    k_zero_i<<<(n_nodes + 255)/256, 256, 0, stream>>>(deg, n_nodes);
    k_count<<<1024, 256, 0, stream>>>(ef, er, deg, Ef, Er);
    k_chunk_sums<<<nch, 256, 0, stream>>>(deg, csum, n_nodes);
    k_scan_chunks<<<1, 1024, 0, stream>>>(csum, nch);
    k_rowstart<<<(n_nodes + 256)/256, 256, 0, stream>>>(deg, csum, row_start, cursor, n_nodes);
    k_fill<<<1024, 256, 0, stream>>>(ef, er, cursor, srcs, Ef, Er);

    // ---- network ----
    k_in_proj_t<<<nb16, 64, 0, stream>>>(x, in_w, in_b, h, n_nodes);
    for (int l = 0; l < 2; ++l) {
        k_kqv_rel_t<<<nb16, 128, 0, stream>>>(h, kqv_w, kqv_b, krel_w, vrel_w,
                                              qa, krel, vrel, l, n_nodes);
        k_attn<<<n_nodes, 128, 0, stream>>>(srcs, row_start, krel, vrel, p_rel,
                                            qa, l, n_nodes);
        k_out_proj_t<<<nb16, 64, 0, stream>>>(qa, out_w, out_b, skip, h, l, n_nodes);
    }
    k_head<<<n_nodes, 64, 0, stream>>>(h, head_w, head_b, out, n_nodes);
}

// Round 6
// 905.592 us; speedup vs baseline: 2.4010x; 1.1663x over previous
//
#include <hip/hip_runtime.h>
#include <math.h>

// ---------------- CSR build ----------------
__global__ void k_zero_i(int* __restrict__ p, int n)
{
    for (int i = blockIdx.x*blockDim.x + threadIdx.x; i < n; i += gridDim.x*blockDim.x)
        p[i] = 0;
}

__global__ void k_count(const int* __restrict__ ef, const int* __restrict__ er,
                        int* __restrict__ deg, int Ef, int Er)
{
    int Etot = Ef + Er;
    for (int e = blockIdx.x*blockDim.x + threadIdx.x; e < Etot; e += gridDim.x*blockDim.x) {
        int dst = (e < Ef) ? ef[Ef + e] : er[Er + (e - Ef)];
        atomicAdd(&deg[dst], 1);
    }
}

__global__ void k_chunk_sums(const int* __restrict__ deg, int* __restrict__ csum, int n)
{
    __shared__ int s[256];
    int t = threadIdx.x, i = blockIdx.x*256 + t;
    s[t] = (i < n) ? deg[i] : 0;
    __syncthreads();
    for (int off = 128; off > 0; off >>= 1) {
        if (t < off) s[t] += s[t + off];
        __syncthreads();
    }
    if (t == 0) csum[blockIdx.x] = s[0];
}

__global__ void k_scan_chunks(int* __restrict__ csum, int nch)
{
    __shared__ int s[1024];
    int t = threadIdx.x;
    int v = (t < nch) ? csum[t] : 0;
    s[t] = v; __syncthreads();
    for (int off = 1; off < 1024; off <<= 1) {
        int u = (t >= off) ? s[t - off] : 0;
        __syncthreads();
        s[t] += u;
        __syncthreads();
    }
    if (t < nch) csum[t] = s[t] - v;
}

__global__ void k_rowstart(const int* __restrict__ deg, const int* __restrict__ csum,
                           int* __restrict__ row_start, int* __restrict__ cursor, int n)
{
    __shared__ int s[256];
    int t = threadIdx.x, i = blockIdx.x*256 + t;
    int d = (i < n) ? deg[i] : 0;
    s[t] = d; __syncthreads();
    for (int off = 1; off < 256; off <<= 1) {
        int u = (t >= off) ? s[t - off] : 0;
        __syncthreads();
        s[t] += u;
        __syncthreads();
    }
    if (i <= n) {
        int rs = csum[blockIdx.x] + s[t] - d;   // exclusive
        row_start[i] = rs;
        cursor[i] = rs;
    }
}

__global__ void k_fill(const int* __restrict__ ef, const int* __restrict__ er,
                       int* __restrict__ cursor, unsigned* __restrict__ srcs,
                       int Ef, int Er)
{
    int Etot = Ef + Er;
    for (int e = blockIdx.x*blockDim.x + threadIdx.x; e < Etot; e += gridDim.x*blockDim.x) {
        int src, dst; unsigned tbit;
        if (e < Ef) { src = ef[e]; dst = ef[Ef + e]; tbit = 0u; }
        else { int e2 = e - Ef; src = er[e2]; dst = er[Er + e2]; tbit = 0x80000000u; }
        int pos = atomicAdd(&cursor[dst], 1);
        srcs[pos] = (unsigned)src | tbit;
    }
}

// ---------------- composed weights ----------------
// Wc[l] is 129 x 640 (row 128 = bias):
//   cols   0-127: q        (kqv_w cols 128..255)
//   cols 128-383: krel t=0,1  = Wk @ krel_w[l][t]  (head-block-diagonal compose)
//   cols 384-639: vrel t=0,1  = Wv @ vrel_w[l][t]
__global__ void k_compose(const float* __restrict__ kqv_w, const float* __restrict__ kqv_b,
                          const float* __restrict__ krel_w, const float* __restrict__ vrel_w,
                          float* __restrict__ Wc)
{
    int idx = blockIdx.x*blockDim.x + threadIdx.x;
    int tot = 2*129*640;
    if (idx >= tot) return;
    int l = idx / (129*640);
    int rem = idx % (129*640);
    int r = rem / 640, c = rem % 640;
    float val;
    if (c < 128) {
        val = (r < 128) ? kqv_w[((size_t)l*128 + r)*384 + 128 + c]
                        : kqv_b[l*384 + 128 + c];
    } else {
        int c2 = c - 128;
        int part = c2 >> 8;            // 0 = krel, 1 = vrel
        int cc = c2 & 255;
        int tt = cc >> 7;
        int ccc = cc & 127;
        int h = ccc >> 4, f = ccc & 15;
        const float* rw = (part == 0 ? krel_w : vrel_w)
                          + (((size_t)(l*2 + tt)*8 + h)*16)*16 + f;
        int base_col = (part == 0 ? 0 : 256) + h*16;
        float s = 0.f;
        #pragma unroll
        for (int d = 0; d < 16; ++d) {
            float a = (r < 128) ? kqv_w[((size_t)l*128 + r)*384 + base_col + d]
                                : kqv_b[l*384 + base_col + d];
            s += a * rw[d*16];
        }
        val = s;
    }
    Wc[idx] = val;
}

// ---------------- tiled GEMM: C[n, :] = A[n, :128] @ W[128, Ncols] + bias ----------------
// BM=32, BN=64, BK=32; 256 threads; thread (tx,ty) computes 2 rows x 4 cols.
// mode 0: plain store to out0[n*128 + c]
// mode 1: routed store (kqv composed: q / krel / vrel)
// mode 2: out0 = h: h = relu(g*C + (1-g)*h), g = sigmoid(skip[l])
__global__ __launch_bounds__(256) void k_gemm(
    const float* __restrict__ A, const float* __restrict__ W, int ldw,
    const float* __restrict__ bias, float* __restrict__ out0,
    float* __restrict__ krel, float* __restrict__ vrel,
    const float* __restrict__ skip, int l,
    int n_nodes, int ncol_tiles, int mode)
{
    __shared__ float As[32][132];
    __shared__ float Ws[32][64];
    int tile_n = blockIdx.x / ncol_tiles;
    int tile_c = blockIdx.x % ncol_tiles;
    int n0 = tile_n*32, c0 = tile_c*64;
    int t = threadIdx.x, tx = t & 15, ty = t >> 4;

    for (int idx = t; idx < 32*128; idx += 256) {
        int r = idx >> 7, c = idx & 127;
        int n = n0 + r;
        As[r][c] = (n < n_nodes) ? A[(size_t)n*128 + c] : 0.f;
    }
    float4 acc0 = *(const float4*)&bias[c0 + tx*4];
    float4 acc1 = acc0;

    for (int kk = 0; kk < 128; kk += 32) {
        __syncthreads();
        #pragma unroll
        for (int i = 0; i < 8; ++i) {
            int r = (t >> 6) + i*4;
            int c = t & 63;
            Ws[r][c] = W[(size_t)(kk + r)*ldw + c0 + c];
        }
        __syncthreads();
        #pragma unroll
        for (int k = 0; k < 32; ++k) {
            float a0 = As[ty*2][kk + k];
            float a1 = As[ty*2 + 1][kk + k];
            float4 w = *(const float4*)&Ws[k][tx*4];
            acc0.x += a0*w.x; acc0.y += a0*w.y; acc0.z += a0*w.z; acc0.w += a0*w.w;
            acc1.x += a1*w.x; acc1.y += a1*w.y; acc1.z += a1*w.z; acc1.w += a1*w.w;
        }
    }

    int n0r = n0 + ty*2;
    if (mode == 1) {
        float* dst; int coff;
        if (c0 < 128)      { dst = out0; coff = c0; }
        else if (c0 < 384) { int tt = (c0 - 128) >> 7;
                             dst = krel + (size_t)tt*n_nodes*128; coff = (c0 - 128) & 127; }
        else               { int tt = (c0 - 384) >> 7;
                             dst = vrel + (size_t)tt*n_nodes*128; coff = (c0 - 384) & 127; }
        if (n0r < n_nodes)     *(float4*)&dst[(size_t)n0r*128 + coff + tx*4] = acc0;
        if (n0r + 1 < n_nodes) *(float4*)&dst[(size_t)(n0r+1)*128 + coff + tx*4] = acc1;
    } else if (mode == 0) {
        if (n0r < n_nodes)     *(float4*)&out0[(size_t)n0r*128 + c0 + tx*4] = acc0;
        if (n0r + 1 < n_nodes) *(float4*)&out0[(size_t)(n0r+1)*128 + c0 + tx*4] = acc1;
    } else {
        float g = 1.f/(1.f + expf(-skip[l]));
        if (n0r < n_nodes) {
            float4 hv = *(const float4*)&out0[(size_t)n0r*128 + c0 + tx*4];
            float4 o;
            o.x = fmaxf(g*acc0.x + (1.f - g)*hv.x, 0.f);
            o.y = fmaxf(g*acc0.y + (1.f - g)*hv.y, 0.f);
            o.z = fmaxf(g*acc0.z + (1.f - g)*hv.z, 0.f);
            o.w = fmaxf(g*acc0.w + (1.f - g)*hv.w, 0.f);
            *(float4*)&out0[(size_t)n0r*128 + c0 + tx*4] = o;
        }
        if (n0r + 1 < n_nodes) {
            float4 hv = *(const float4*)&out0[(size_t)(n0r+1)*128 + c0 + tx*4];
            float4 o;
            o.x = fmaxf(g*acc1.x + (1.f - g)*hv.x, 0.f);
            o.y = fmaxf(g*acc1.y + (1.f - g)*hv.y, 0.f);
            o.z = fmaxf(g*acc1.z + (1.f - g)*hv.z, 0.f);
            o.w = fmaxf(g*acc1.w + (1.f - g)*hv.w, 0.f);
            *(float4*)&out0[(size_t)(n0r+1)*128 + c0 + tx*4] = o;
        }
    }
}

// ---------------- fused gather attention (online softmax + gelu) ----------------
__global__ __launch_bounds__(128) void k_attn(
    const unsigned* __restrict__ srcs, const int* __restrict__ row_start,
    const float* __restrict__ krel, const float* __restrict__ vrel,
    const float* __restrict__ p_rel, float* __restrict__ qa, int l, int n_nodes)
{
    int n = blockIdx.x;
    if (n >= n_nodes) return;
    int t = threadIdx.x, hd = t >> 4;
    float qv = qa[(size_t)n*128 + t];
    float p0 = p_rel[(2*l)*8 + hd] * 0.25f;
    float p1 = p_rel[(2*l + 1)*8 + hd] * 0.25f;
    int s = row_start[n], e = row_start[n + 1];
    float m = -INFINITY, lsum = 0.f, acc = 0.f;
    for (int pos = s; pos < e; ++pos) {
        unsigned sv = srcs[pos];
        int src = (int)(sv & 0x7fffffffu);
        int tt = (int)(sv >> 31);
        size_t bofs = ((size_t)tt*n_nodes + src)*128 + t;
        float kv = krel[bofs];
        float vv = vrel[bofs];
        float d = qv*kv;
        d += __shfl_xor(d, 1); d += __shfl_xor(d, 2);
        d += __shfl_xor(d, 4); d += __shfl_xor(d, 8);
        float a = d * (tt ? p1 : p0);
        float mn = fmaxf(m, a);
        float sc = expf(m - mn);
        float w  = expf(a - mn);
        lsum = lsum*sc + w;
        acc  = acc*sc + w*vv;
        m = mn;
    }
    float xo = acc / (lsum + 1e-16f);
    qa[(size_t)n*128 + t] = 0.5f*xo*(1.f + erff(xo*0.70710678118654752f));
}

// head: one wave per node, shuffle reduce
__global__ __launch_bounds__(64) void k_head(
    const float* __restrict__ h, const float* __restrict__ hw,
    const float* __restrict__ hb, float* __restrict__ out, int n_nodes)
{
    int n = blockIdx.x;
    if (n >= n_nodes) return;
    int t = threadIdx.x;
    float h0 = h[(size_t)n*128 + t], h1 = h[(size_t)n*128 + 64 + t];
    float c0 = h0*hw[t*2]     + h1*hw[(t+64)*2];
    float c1 = h0*hw[t*2 + 1] + h1*hw[(t+64)*2 + 1];
    for (int off = 32; off > 0; off >>= 1) {
        c0 += __shfl_down(c0, off);
        c1 += __shfl_down(c1, off);
    }
    if (t == 0) {
        out[n*2]     = c0 + hb[0];
        out[n*2 + 1] = c1 + hb[1];
    }
}

extern "C" void kernel_launch(void* const* d_in, const int* in_sizes, int n_in,
                              void* d_out, int out_size, void* d_ws, size_t ws_size,
                              hipStream_t stream)
{
    const float* x      = (const float*)d_in[0];
    const int*   ef     = (const int*)d_in[1];
    const int*   er     = (const int*)d_in[2];
    const float* in_w   = (const float*)d_in[3];
    const float* in_b   = (const float*)d_in[4];
    const float* kqv_w  = (const float*)d_in[5];
    const float* kqv_b  = (const float*)d_in[6];
    const float* krel_w = (const float*)d_in[7];
    const float* vrel_w = (const float*)d_in[8];
    const float* p_rel  = (const float*)d_in[9];
    const float* out_w  = (const float*)d_in[10];
    const float* out_b  = (const float*)d_in[11];
    const float* skip   = (const float*)d_in[12];
    const float* head_w = (const float*)d_in[13];
    const float* head_b = (const float*)d_in[14];
    float* out = (float*)d_out;

    int n_nodes = in_sizes[0] / 128;
    int Ef = in_sizes[1] / 2, Er = in_sizes[2] / 2;
    int Etot = Ef + Er;
    int nch = (n_nodes + 255)/256;

    // workspace
    float* p = (float*)d_ws;
    float* h    = p; p += (size_t)n_nodes*128;
    float* qa   = p; p += (size_t)n_nodes*128;
    float* krel = p; p += (size_t)2*n_nodes*128;
    float* vrel = p; p += (size_t)2*n_nodes*128;
    float* Wc   = p; p += (size_t)2*129*640;
    int* deg       = (int*)p;      p += n_nodes;
    int* csum      = (int*)p;      p += 1024;
    int* row_start = (int*)p;      p += n_nodes + 1;
    int* cursor    = (int*)p;      p += n_nodes + 1;
    unsigned* srcs = (unsigned*)p; p += Etot;

    int ntile = (n_nodes + 31)/32;

    // ---- CSR build + weight compose (independent of layers) ----
    k_zero_i<<<(n_nodes + 255)/256, 256, 0, stream>>>(deg, n_nodes);
    k_count<<<1024, 256, 0, stream>>>(ef, er, deg, Ef, Er);
    k_chunk_sums<<<nch, 256, 0, stream>>>(deg, csum, n_nodes);
    k_scan_chunks<<<1, 1024, 0, stream>>>(csum, nch);
    k_rowstart<<<(n_nodes + 256)/256, 256, 0, stream>>>(deg, csum, row_start, cursor, n_nodes);
    k_fill<<<1024, 256, 0, stream>>>(ef, er, cursor, srcs, Ef, Er);
    k_compose<<<(2*129*640 + 255)/256, 256, 0, stream>>>(kqv_w, kqv_b, krel_w, vrel_w, Wc);

    // ---- network ----
    k_gemm<<<ntile*2, 256, 0, stream>>>(x, in_w, 128, in_b, h,
                                        nullptr, nullptr, skip, 0, n_nodes, 2, 0);
    for (int l = 0; l < 2; ++l) {
        const float* Wl = Wc + (size_t)l*129*640;
        k_gemm<<<ntile*10, 256, 0, stream>>>(h, Wl, 640, Wl + 128*640, qa,
                                             krel, vrel, skip, l, n_nodes, 10, 1);
        k_attn<<<n_nodes, 128, 0, stream>>>(srcs, row_start, krel, vrel, p_rel,
                                            qa, l, n_nodes);
        k_gemm<<<ntile*2, 256, 0, stream>>>(qa, out_w + (size_t)l*128*128, 128,
                                            out_b + (size_t)l*128, h,
                                            nullptr, nullptr, skip, l, n_nodes, 2, 2);
    }
    k_head<<<n_nodes, 64, 0, stream>>>(h, head_w, head_b, out, n_nodes);
}

// Round 7
// 759.014 us; speedup vs baseline: 2.8647x; 1.1931x over previous
//
#include <hip/hip_runtime.h>
#include <math.h>

// ---------------- CSR build ----------------
__global__ void k_zero_i(int* __restrict__ p, int n)
{
    for (int i = blockIdx.x*blockDim.x + threadIdx.x; i < n; i += gridDim.x*blockDim.x)
        p[i] = 0;
}

__global__ void k_count(const int* __restrict__ ef, const int* __restrict__ er,
                        int* __restrict__ deg, int Ef, int Er)
{
    int Etot = Ef + Er;
    for (int e = blockIdx.x*blockDim.x + threadIdx.x; e < Etot; e += gridDim.x*blockDim.x) {
        int dst = (e < Ef) ? ef[Ef + e] : er[Er + (e - Ef)];
        atomicAdd(&deg[dst], 1);
    }
}

__global__ void k_chunk_sums(const int* __restrict__ deg, int* __restrict__ csum, int n)
{
    __shared__ int s[256];
    int t = threadIdx.x, i = blockIdx.x*256 + t;
    s[t] = (i < n) ? deg[i] : 0;
    __syncthreads();
    for (int off = 128; off > 0; off >>= 1) {
        if (t < off) s[t] += s[t + off];
        __syncthreads();
    }
    if (t == 0) csum[blockIdx.x] = s[0];
}

__global__ void k_scan_chunks(int* __restrict__ csum, int nch)
{
    __shared__ int s[1024];
    int t = threadIdx.x;
    int v = (t < nch) ? csum[t] : 0;
    s[t] = v; __syncthreads();
    for (int off = 1; off < 1024; off <<= 1) {
        int u = (t >= off) ? s[t - off] : 0;
        __syncthreads();
        s[t] += u;
        __syncthreads();
    }
    if (t < nch) csum[t] = s[t] - v;
}

__global__ void k_rowstart(const int* __restrict__ deg, const int* __restrict__ csum,
                           int* __restrict__ row_start, int* __restrict__ cursor, int n)
{
    __shared__ int s[256];
    int t = threadIdx.x, i = blockIdx.x*256 + t;
    int d = (i < n) ? deg[i] : 0;
    s[t] = d; __syncthreads();
    for (int off = 1; off < 256; off <<= 1) {
        int u = (t >= off) ? s[t - off] : 0;
        __syncthreads();
        s[t] += u;
        __syncthreads();
    }
    if (i <= n) {
        int rs = csum[blockIdx.x] + s[t] - d;   // exclusive
        row_start[i] = rs;
        cursor[i] = rs;
    }
}

__global__ void k_fill(const int* __restrict__ ef, const int* __restrict__ er,
                       int* __restrict__ cursor, unsigned* __restrict__ srcs,
                       int Ef, int Er)
{
    int Etot = Ef + Er;
    for (int e = blockIdx.x*blockDim.x + threadIdx.x; e < Etot; e += gridDim.x*blockDim.x) {
        int src, dst; unsigned tbit;
        if (e < Ef) { src = ef[e]; dst = ef[Ef + e]; tbit = 0u; }
        else { int e2 = e - Ef; src = er[e2]; dst = er[Er + e2]; tbit = 0x80000000u; }
        int pos = atomicAdd(&cursor[dst], 1);
        srcs[pos] = (unsigned)src | tbit;
    }
}

// ---------------- composed weights ----------------
// Wc[l] is 129 x 640 (row 128 = bias):
//   cols   0-127: q
//   cols 128-383: krel t=0,1 = Wk @ krel_w[l][t]  (scaled by p_rel[l,t,h]*0.25)
//   cols 384-639: vrel t=0,1 = Wv @ vrel_w[l][t]
__global__ void k_compose(const float* __restrict__ kqv_w, const float* __restrict__ kqv_b,
                          const float* __restrict__ krel_w, const float* __restrict__ vrel_w,
                          const float* __restrict__ p_rel, float* __restrict__ Wc)
{
    int idx = blockIdx.x*blockDim.x + threadIdx.x;
    int tot = 2*129*640;
    if (idx >= tot) return;
    int l = idx / (129*640);
    int rem = idx % (129*640);
    int r = rem / 640, c = rem % 640;
    float val;
    if (c < 128) {
        val = (r < 128) ? kqv_w[((size_t)l*128 + r)*384 + 128 + c]
                        : kqv_b[l*384 + 128 + c];
    } else {
        int c2 = c - 128;
        int part = c2 >> 8;            // 0 = krel, 1 = vrel
        int cc = c2 & 255;
        int tt = cc >> 7;
        int ccc = cc & 127;
        int h = ccc >> 4, f = ccc & 15;
        const float* rw = (part == 0 ? krel_w : vrel_w)
                          + (((size_t)(l*2 + tt)*8 + h)*16)*16 + f;
        int base_col = (part == 0 ? 0 : 256) + h*16;
        float s = 0.f;
        #pragma unroll
        for (int d = 0; d < 16; ++d) {
            float a = (r < 128) ? kqv_w[((size_t)l*128 + r)*384 + base_col + d]
                                : kqv_b[l*384 + base_col + d];
            s += a * rw[d*16];
        }
        // fold alpha scale p*1/sqrt(D) into krel (applies to bias too)
        if (part == 0) s *= p_rel[(l*2 + tt)*8 + h] * 0.25f;
        val = s;
    }
    Wc[idx] = val;
}

// ---------------- tiled GEMM: C = A[.,128] @ W[128, ncols] + bias ----------------
// BM=64, BN=64, BK=32; 256 threads; thread (tx,ty) computes 4 rows x 4 cols.
// A staged transposed (As_t[k][m]) so inner reads are ds_read_b128 both sides.
// mode 0: plain store; mode 1: routed (q/krel/vrel); mode 2: h=relu(g*C+(1-g)*h)
__global__ __launch_bounds__(256) void k_gemm(
    const float* __restrict__ A, const float* __restrict__ W, int ldw,
    const float* __restrict__ bias, float* __restrict__ out0,
    float* __restrict__ krel, float* __restrict__ vrel,
    const float* __restrict__ skip, int l,
    int n_nodes, int ncol_tiles, int mode)
{
    __shared__ float As_t[32][68];
    __shared__ float Ws[32][64];
    int tile_n = blockIdx.x / ncol_tiles;
    int tile_c = blockIdx.x % ncol_tiles;
    int n0 = tile_n*64, c0 = tile_c*64;
    int t = threadIdx.x, tx = t & 15, ty = t >> 4;

    float4 b4 = *(const float4*)&bias[c0 + tx*4];
    float acc[4][4];
    #pragma unroll
    for (int r = 0; r < 4; ++r) {
        acc[r][0] = b4.x; acc[r][1] = b4.y; acc[r][2] = b4.z; acc[r][3] = b4.w;
    }

    for (int kk = 0; kk < 128; kk += 32) {
        __syncthreads();
        #pragma unroll
        for (int it = 0; it < 2; ++it) {
            int idx = t + it*256;          // [0,512)
            int m = idx >> 3, c4 = idx & 7;
            int n = n0 + m;
            float4 a = make_float4(0.f, 0.f, 0.f, 0.f);
            if (n < n_nodes) a = *(const float4*)&A[(size_t)n*128 + kk + c4*4];
            As_t[c4*4 + 0][m] = a.x;
            As_t[c4*4 + 1][m] = a.y;
            As_t[c4*4 + 2][m] = a.z;
            As_t[c4*4 + 3][m] = a.w;
        }
        #pragma unroll
        for (int it = 0; it < 2; ++it) {
            int idx = t + it*256;          // [0,512)
            int r = idx >> 4, c4 = idx & 15;
            *(float4*)&Ws[r][c4*4] = *(const float4*)&W[(size_t)(kk + r)*ldw + c0 + c4*4];
        }
        __syncthreads();
        #pragma unroll 8
        for (int k = 0; k < 32; ++k) {
            float4 a = *(const float4*)&As_t[k][ty*4];
            float4 w = *(const float4*)&Ws[k][tx*4];
            acc[0][0] += a.x*w.x; acc[0][1] += a.x*w.y; acc[0][2] += a.x*w.z; acc[0][3] += a.x*w.w;
            acc[1][0] += a.y*w.x; acc[1][1] += a.y*w.y; acc[1][2] += a.y*w.z; acc[1][3] += a.y*w.w;
            acc[2][0] += a.z*w.x; acc[2][1] += a.z*w.y; acc[2][2] += a.z*w.z; acc[2][3] += a.z*w.w;
            acc[3][0] += a.w*w.x; acc[3][1] += a.w*w.y; acc[3][2] += a.w*w.z; acc[3][3] += a.w*w.w;
        }
    }

    float* dst; int coff; size_t stride128 = 128;
    if (mode == 1) {
        if (c0 < 128)      { dst = out0; coff = c0; }
        else if (c0 < 384) { int tt = (c0 - 128) >> 7;
                             dst = krel + (size_t)tt*n_nodes*128; coff = (c0 - 128) & 127; }
        else               { int tt = (c0 - 384) >> 7;
                             dst = vrel + (size_t)tt*n_nodes*128; coff = (c0 - 384) & 127; }
    } else { dst = out0; coff = c0; }

    if (mode == 2) {
        float g = 1.f/(1.f + expf(-skip[l]));
        #pragma unroll
        for (int r = 0; r < 4; ++r) {
            int n = n0 + ty*4 + r;
            if (n >= n_nodes) break;
            float4 hv = *(const float4*)&dst[(size_t)n*stride128 + coff + tx*4];
            float4 o;
            o.x = fmaxf(g*acc[r][0] + (1.f - g)*hv.x, 0.f);
            o.y = fmaxf(g*acc[r][1] + (1.f - g)*hv.y, 0.f);
            o.z = fmaxf(g*acc[r][2] + (1.f - g)*hv.z, 0.f);
            o.w = fmaxf(g*acc[r][3] + (1.f - g)*hv.w, 0.f);
            *(float4*)&dst[(size_t)n*stride128 + coff + tx*4] = o;
        }
    } else {
        #pragma unroll
        for (int r = 0; r < 4; ++r) {
            int n = n0 + ty*4 + r;
            if (n >= n_nodes) break;
            float4 o = make_float4(acc[r][0], acc[r][1], acc[r][2], acc[r][3]);
            *(float4*)&dst[(size_t)n*stride128 + coff + tx*4] = o;
        }
    }
}

// ---------------- fused gather attention (online softmax + gelu) ----------------
// p*scale pre-folded into krel; 2-edge unrolled recurrence.
__global__ __launch_bounds__(128) void k_attn(
    const unsigned* __restrict__ srcs, const int* __restrict__ row_start,
    const float* __restrict__ krel, const float* __restrict__ vrel,
    float* __restrict__ qa, int n_nodes)
{
    int n = blockIdx.x;
    if (n >= n_nodes) return;
    int t = threadIdx.x;
    float qv = qa[(size_t)n*128 + t];
    int s = row_start[n], e = row_start[n + 1];
    float m = -INFINITY, lsum = 0.f, acc = 0.f;
    int pos = s;
    for (; pos + 1 < e; pos += 2) {
        unsigned sv0 = srcs[pos], sv1 = srcs[pos + 1];
        size_t b0 = (((size_t)(sv0 >> 31))*n_nodes + (sv0 & 0x7fffffffu))*128 + t;
        size_t b1 = (((size_t)(sv1 >> 31))*n_nodes + (sv1 & 0x7fffffffu))*128 + t;
        float k0 = krel[b0], v0 = vrel[b0];
        float k1 = krel[b1], v1 = vrel[b1];
        float d0 = qv*k0, d1 = qv*k1;
        d0 += __shfl_xor(d0, 1); d1 += __shfl_xor(d1, 1);
        d0 += __shfl_xor(d0, 2); d1 += __shfl_xor(d1, 2);
        d0 += __shfl_xor(d0, 4); d1 += __shfl_xor(d1, 4);
        d0 += __shfl_xor(d0, 8); d1 += __shfl_xor(d1, 8);
        float mn = fmaxf(m, fmaxf(d0, d1));
        float sc = expf(m - mn);
        float w0 = expf(d0 - mn), w1 = expf(d1 - mn);
        lsum = lsum*sc + w0 + w1;
        acc  = acc*sc + w0*v0 + w1*v1;
        m = mn;
    }
    if (pos < e) {
        unsigned sv = srcs[pos];
        size_t b0 = (((size_t)(sv >> 31))*n_nodes + (sv & 0x7fffffffu))*128 + t;
        float k0 = krel[b0], v0 = vrel[b0];
        float d = qv*k0;
        d += __shfl_xor(d, 1); d += __shfl_xor(d, 2);
        d += __shfl_xor(d, 4); d += __shfl_xor(d, 8);
        float mn = fmaxf(m, d);
        float sc = expf(m - mn);
        float w  = expf(d - mn);
        lsum = lsum*sc + w;
        acc  = acc*sc + w*v0;
        m = mn;
    }
    float xo = acc / (lsum + 1e-16f);
    qa[(size_t)n*128 + t] = 0.5f*xo*(1.f + erff(xo*0.70710678118654752f));
}

// head: one wave per node, shuffle reduce
__global__ __launch_bounds__(64) void k_head(
    const float* __restrict__ h, const float* __restrict__ hw,
    const float* __restrict__ hb, float* __restrict__ out, int n_nodes)
{
    int n = blockIdx.x;
    if (n >= n_nodes) return;
    int t = threadIdx.x;
    float h0 = h[(size_t)n*128 + t], h1 = h[(size_t)n*128 + 64 + t];
    float c0 = h0*hw[t*2]     + h1*hw[(t+64)*2];
    float c1 = h0*hw[t*2 + 1] + h1*hw[(t+64)*2 + 1];
    for (int off = 32; off > 0; off >>= 1) {
        c0 += __shfl_down(c0, off);
        c1 += __shfl_down(c1, off);
    }
    if (t == 0) {
        out[n*2]     = c0 + hb[0];
        out[n*2 + 1] = c1 + hb[1];
    }
}

extern "C" void kernel_launch(void* const* d_in, const int* in_sizes, int n_in,
                              void* d_out, int out_size, void* d_ws, size_t ws_size,
                              hipStream_t stream)
{
    const float* x      = (const float*)d_in[0];
    const int*   ef     = (const int*)d_in[1];
    const int*   er     = (const int*)d_in[2];
    const float* in_w   = (const float*)d_in[3];
    const float* in_b   = (const float*)d_in[4];
    const float* kqv_w  = (const float*)d_in[5];
    const float* kqv_b  = (const float*)d_in[6];
    const float* krel_w = (const float*)d_in[7];
    const float* vrel_w = (const float*)d_in[8];
    const float* p_rel  = (const float*)d_in[9];
    const float* out_w  = (const float*)d_in[10];
    const float* out_b  = (const float*)d_in[11];
    const float* skip   = (const float*)d_in[12];
    const float* head_w = (const float*)d_in[13];
    const float* head_b = (const float*)d_in[14];
    float* out = (float*)d_out;

    int n_nodes = in_sizes[0] / 128;
    int Ef = in_sizes[1] / 2, Er = in_sizes[2] / 2;
    int Etot = Ef + Er;
    int nch = (n_nodes + 255)/256;

    // workspace
    float* p = (float*)d_ws;
    float* h    = p; p += (size_t)n_nodes*128;
    float* qa   = p; p += (size_t)n_nodes*128;
    float* krel = p; p += (size_t)2*n_nodes*128;
    float* vrel = p; p += (size_t)2*n_nodes*128;
    float* Wc   = p; p += (size_t)2*129*640;
    int* deg       = (int*)p;      p += n_nodes;
    int* csum      = (int*)p;      p += 1024;
    int* row_start = (int*)p;      p += n_nodes + 1;
    int* cursor    = (int*)p;      p += n_nodes + 1;
    unsigned* srcs = (unsigned*)p; p += Etot;

    int ntile = (n_nodes + 63)/64;

    // ---- CSR build + weight compose ----
    k_zero_i<<<(n_nodes + 255)/256, 256, 0, stream>>>(deg, n_nodes);
    k_count<<<1024, 256, 0, stream>>>(ef, er, deg, Ef, Er);
    k_chunk_sums<<<nch, 256, 0, stream>>>(deg, csum, n_nodes);
    k_scan_chunks<<<1, 1024, 0, stream>>>(csum, nch);
    k_rowstart<<<(n_nodes + 256)/256, 256, 0, stream>>>(deg, csum, row_start, cursor, n_nodes);
    k_fill<<<1024, 256, 0, stream>>>(ef, er, cursor, srcs, Ef, Er);
    k_compose<<<(2*129*640 + 255)/256, 256, 0, stream>>>(kqv_w, kqv_b, krel_w, vrel_w,
                                                         p_rel, Wc);

    // ---- network ----
    k_gemm<<<ntile*2, 256, 0, stream>>>(x, in_w, 128, in_b, h,
                                        nullptr, nullptr, skip, 0, n_nodes, 2, 0);
    for (int l = 0; l < 2; ++l) {
        const float* Wl = Wc + (size_t)l*129*640;
        k_gemm<<<ntile*10, 256, 0, stream>>>(h, Wl, 640, Wl + 128*640, qa,
                                             krel, vrel, skip, l, n_nodes, 10, 1);
        k_attn<<<n_nodes, 128, 0, stream>>>(srcs, row_start, krel, vrel, qa, n_nodes);
        k_gemm<<<ntile*2, 256, 0, stream>>>(qa, out_w + (size_t)l*128*128, 128,
                                            out_b + (size_t)l*128, h,
                                            nullptr, nullptr, skip, l, n_nodes, 2, 2);
    }
    k_head<<<n_nodes, 64, 0, stream>>>(h, head_w, head_b, out, n_nodes);
}

// Round 8
// 692.844 us; speedup vs baseline: 3.1383x; 1.0955x over previous
//
#include <hip/hip_runtime.h>
#include <math.h>

// ---------------- helpers ----------------
__device__ __forceinline__ unsigned short f2bf(float f){   // RTN bf16
    unsigned u = __float_as_uint(f);
    unsigned r = u + 0x7fffu + ((u >> 16) & 1u);
    return (unsigned short)(r >> 16);
}

// ---------------- CSR build ----------------
__global__ void k_zero_i(int* __restrict__ p, int n)
{
    for (int i = blockIdx.x*blockDim.x + threadIdx.x; i < n; i += gridDim.x*blockDim.x)
        p[i] = 0;
}

__global__ void k_count(const int* __restrict__ ef, const int* __restrict__ er,
                        int* __restrict__ deg, int Ef, int Er)
{
    int Etot = Ef + Er;
    for (int e = blockIdx.x*blockDim.x + threadIdx.x; e < Etot; e += gridDim.x*blockDim.x) {
        int dst = (e < Ef) ? ef[Ef + e] : er[Er + (e - Ef)];
        atomicAdd(&deg[dst], 1);
    }
}

__global__ void k_chunk_sums(const int* __restrict__ deg, int* __restrict__ csum, int n)
{
    __shared__ int s[256];
    int t = threadIdx.x, i = blockIdx.x*256 + t;
    s[t] = (i < n) ? deg[i] : 0;
    __syncthreads();
    for (int off = 128; off > 0; off >>= 1) {
        if (t < off) s[t] += s[t + off];
        __syncthreads();
    }
    if (t == 0) csum[blockIdx.x] = s[0];
}

__global__ void k_scan_chunks(int* __restrict__ csum, int nch)
{
    __shared__ int s[1024];
    int t = threadIdx.x;
    int v = (t < nch) ? csum[t] : 0;
    s[t] = v; __syncthreads();
    for (int off = 1; off < 1024; off <<= 1) {
        int u = (t >= off) ? s[t - off] : 0;
        __syncthreads();
        s[t] += u;
        __syncthreads();
    }
    if (t < nch) csum[t] = s[t] - v;
}

__global__ void k_rowstart(const int* __restrict__ deg, const int* __restrict__ csum,
                           int* __restrict__ row_start, int* __restrict__ cursor, int n)
{
    __shared__ int s[256];
    int t = threadIdx.x, i = blockIdx.x*256 + t;
    int d = (i < n) ? deg[i] : 0;
    s[t] = d; __syncthreads();
    for (int off = 1; off < 256; off <<= 1) {
        int u = (t >= off) ? s[t - off] : 0;
        __syncthreads();
        s[t] += u;
        __syncthreads();
    }
    if (i <= n) {
        int rs = csum[blockIdx.x] + s[t] - d;   // exclusive
        row_start[i] = rs;
        cursor[i] = rs;
    }
}

__global__ void k_fill(const int* __restrict__ ef, const int* __restrict__ er,
                       int* __restrict__ cursor, unsigned* __restrict__ srcs,
                       int Ef, int Er)
{
    int Etot = Ef + Er;
    for (int e = blockIdx.x*blockDim.x + threadIdx.x; e < Etot; e += gridDim.x*blockDim.x) {
        int src, dst; unsigned tbit;
        if (e < Ef) { src = ef[e]; dst = ef[Ef + e]; tbit = 0u; }
        else { int e2 = e - Ef; src = er[e2]; dst = er[Er + e2]; tbit = 0x80000000u; }
        int pos = atomicAdd(&cursor[dst], 1);
        srcs[pos] = (unsigned)src | tbit;
    }
}

// ---------------- composed weights ----------------
// Wc[l] 129 x 640 (row 128 = bias): q | krel(t=0,1, p*scale folded) | vrel(t=0,1)
__global__ void k_compose(const float* __restrict__ kqv_w, const float* __restrict__ kqv_b,
                          const float* __restrict__ krel_w, const float* __restrict__ vrel_w,
                          const float* __restrict__ p_rel, float* __restrict__ Wc)
{
    int idx = blockIdx.x*blockDim.x + threadIdx.x;
    int tot = 2*129*640;
    if (idx >= tot) return;
    int l = idx / (129*640);
    int rem = idx % (129*640);
    int r = rem / 640, c = rem % 640;
    float val;
    if (c < 128) {
        val = (r < 128) ? kqv_w[((size_t)l*128 + r)*384 + 128 + c]
                        : kqv_b[l*384 + 128 + c];
    } else {
        int c2 = c - 128;
        int part = c2 >> 8;            // 0 = krel, 1 = vrel
        int cc = c2 & 255;
        int tt = cc >> 7;
        int ccc = cc & 127;
        int h = ccc >> 4, f = ccc & 15;
        const float* rw = (part == 0 ? krel_w : vrel_w)
                          + (((size_t)(l*2 + tt)*8 + h)*16)*16 + f;
        int base_col = (part == 0 ? 0 : 256) + h*16;
        float s = 0.f;
        #pragma unroll
        for (int d = 0; d < 16; ++d) {
            float a = (r < 128) ? kqv_w[((size_t)l*128 + r)*384 + base_col + d]
                                : kqv_b[l*384 + base_col + d];
            s += a * rw[d*16];
        }
        if (part == 0) s *= p_rel[(l*2 + tt)*8 + h] * 0.25f;
        val = s;
    }
    Wc[idx] = val;
}

// ---------------- tiled GEMM ----------------
// BM=64, BN=64, BK=32; 256 threads; 4x4 register tile per thread.
// mode 0: plain f32 store; mode 1: q→out0 f32, krel/vrel→bf16 half-stores into kv;
// mode 2: h = relu(g*C + (1-g)*h)
__global__ __launch_bounds__(256) void k_gemm(
    const float* __restrict__ A, const float* __restrict__ W, int ldw,
    const float* __restrict__ bias, float* __restrict__ out0,
    unsigned* __restrict__ kv, const float* __restrict__ skip, int l,
    int n_nodes, int ncol_tiles, int mode)
{
    __shared__ float As_t[32][68];
    __shared__ float Ws[32][64];
    int tile_n = blockIdx.x / ncol_tiles;
    int tile_c = blockIdx.x % ncol_tiles;
    int n0 = tile_n*64, c0 = tile_c*64;
    int t = threadIdx.x, tx = t & 15, ty = t >> 4;

    float4 b4 = *(const float4*)&bias[c0 + tx*4];
    float acc[4][4];
    #pragma unroll
    for (int r = 0; r < 4; ++r) {
        acc[r][0] = b4.x; acc[r][1] = b4.y; acc[r][2] = b4.z; acc[r][3] = b4.w;
    }

    for (int kk = 0; kk < 128; kk += 32) {
        __syncthreads();
        #pragma unroll
        for (int it = 0; it < 2; ++it) {
            int idx = t + it*256;
            int m = idx >> 3, c4 = idx & 7;
            int n = n0 + m;
            float4 a = make_float4(0.f, 0.f, 0.f, 0.f);
            if (n < n_nodes) a = *(const float4*)&A[(size_t)n*128 + kk + c4*4];
            As_t[c4*4 + 0][m] = a.x;
            As_t[c4*4 + 1][m] = a.y;
            As_t[c4*4 + 2][m] = a.z;
            As_t[c4*4 + 3][m] = a.w;
        }
        #pragma unroll
        for (int it = 0; it < 2; ++it) {
            int idx = t + it*256;
            int r = idx >> 4, c4 = idx & 15;
            *(float4*)&Ws[r][c4*4] = *(const float4*)&W[(size_t)(kk + r)*ldw + c0 + c4*4];
        }
        __syncthreads();
        #pragma unroll 8
        for (int k = 0; k < 32; ++k) {
            float4 a = *(const float4*)&As_t[k][ty*4];
            float4 w = *(const float4*)&Ws[k][tx*4];
            acc[0][0] += a.x*w.x; acc[0][1] += a.x*w.y; acc[0][2] += a.x*w.z; acc[0][3] += a.x*w.w;
            acc[1][0] += a.y*w.x; acc[1][1] += a.y*w.y; acc[1][2] += a.y*w.z; acc[1][3] += a.y*w.w;
            acc[2][0] += a.z*w.x; acc[2][1] += a.z*w.y; acc[2][2] += a.z*w.z; acc[2][3] += a.z*w.w;
            acc[3][0] += a.w*w.x; acc[3][1] += a.w*w.y; acc[3][2] += a.w*w.z; acc[3][3] += a.w*w.w;
        }
    }

    if (mode == 1 && c0 >= 128) {
        // pack bf16 halves into kv words: k -> high ushort (+1), v -> low ushort (+0)
        int c2 = c0 - 128;
        int part = c2 >> 8;            // 0 = k, 1 = v
        int tt = (c2 >> 7) & 1;
        int coff = c2 & 127;
        unsigned short* dsth = (unsigned short*)(kv + (size_t)tt*n_nodes*128)
                               + (part ? 0 : 1);
        #pragma unroll
        for (int r = 0; r < 4; ++r) {
            int n = n0 + ty*4 + r;
            if (n >= n_nodes) break;
            size_t base = ((size_t)n*128 + coff + tx*4)*2;
            dsth[base]     = f2bf(acc[r][0]);
            dsth[base + 2] = f2bf(acc[r][1]);
            dsth[base + 4] = f2bf(acc[r][2]);
            dsth[base + 6] = f2bf(acc[r][3]);
        }
    } else if (mode == 2) {
        float g = 1.f/(1.f + expf(-skip[l]));
        #pragma unroll
        for (int r = 0; r < 4; ++r) {
            int n = n0 + ty*4 + r;
            if (n >= n_nodes) break;
            float4 hv = *(const float4*)&out0[(size_t)n*128 + c0 + tx*4];
            float4 o;
            o.x = fmaxf(g*acc[r][0] + (1.f - g)*hv.x, 0.f);
            o.y = fmaxf(g*acc[r][1] + (1.f - g)*hv.y, 0.f);
            o.z = fmaxf(g*acc[r][2] + (1.f - g)*hv.z, 0.f);
            o.w = fmaxf(g*acc[r][3] + (1.f - g)*hv.w, 0.f);
            *(float4*)&out0[(size_t)n*128 + c0 + tx*4] = o;
        }
    } else {
        #pragma unroll
        for (int r = 0; r < 4; ++r) {
            int n = n0 + ty*4 + r;
            if (n >= n_nodes) break;
            float4 o = make_float4(acc[r][0], acc[r][1], acc[r][2], acc[r][3]);
            *(float4*)&out0[(size_t)n*128 + c0 + tx*4] = o;
        }
    }
}

// ---------------- fused gather attention ----------------
// 32 lanes per node (8 nodes per 256-thr block), 4 features/lane (uint4 kv load),
// online softmax (p*scale folded into k at compose), gelu epilogue. qa in/out.
__global__ __launch_bounds__(256) void k_attn(
    const unsigned* __restrict__ srcs, const int* __restrict__ row_start,
    const uint4* __restrict__ kv, float* __restrict__ qa, int n_nodes)
{
    int lane = threadIdx.x & 31;
    int n = blockIdx.x*8 + (threadIdx.x >> 5);
    if (n >= n_nodes) return;
    float4 q4 = *(const float4*)&qa[(size_t)n*128 + lane*4];
    int s = row_start[n], e = row_start[n + 1];
    float m = -INFINITY, lsum = 0.f;
    float4 acc = make_float4(0.f, 0.f, 0.f, 0.f);

    uint4 w4n; 
    if (s < e) {
        unsigned sv = srcs[s];
        w4n = kv[(((size_t)(sv >> 31))*n_nodes + (sv & 0x7fffffffu))*32 + lane];
    }
    for (int pos = s; pos < e; ) {
        uint4 w4 = w4n;
        ++pos;
        if (pos < e) {
            unsigned sv = srcs[pos];
            w4n = kv[(((size_t)(sv >> 31))*n_nodes + (sv & 0x7fffffffu))*32 + lane];
        }
        float d = __uint_as_float(w4.x & 0xffff0000u)*q4.x
                + __uint_as_float(w4.y & 0xffff0000u)*q4.y
                + __uint_as_float(w4.z & 0xffff0000u)*q4.z
                + __uint_as_float(w4.w & 0xffff0000u)*q4.w;
        d += __shfl_xor(d, 1);
        d += __shfl_xor(d, 2);
        float mn = fmaxf(m, d);
        float sc = __expf(m - mn);
        float w  = __expf(d - mn);
        lsum = lsum*sc + w;
        acc.x = acc.x*sc + w*__uint_as_float(w4.x << 16);
        acc.y = acc.y*sc + w*__uint_as_float(w4.y << 16);
        acc.z = acc.z*sc + w*__uint_as_float(w4.z << 16);
        acc.w = acc.w*sc + w*__uint_as_float(w4.w << 16);
        m = mn;
    }
    float inv = 1.f/(lsum + 1e-16f);
    float4 o;
    float x0 = acc.x*inv, x1 = acc.y*inv, x2 = acc.z*inv, x3 = acc.w*inv;
    o.x = 0.5f*x0*(1.f + erff(x0*0.70710678118654752f));
    o.y = 0.5f*x1*(1.f + erff(x1*0.70710678118654752f));
    o.z = 0.5f*x2*(1.f + erff(x2*0.70710678118654752f));
    o.w = 0.5f*x3*(1.f + erff(x3*0.70710678118654752f));
    *(float4*)&qa[(size_t)n*128 + lane*4] = o;
}

// head: one wave per node, shuffle reduce
__global__ __launch_bounds__(64) void k_head(
    const float* __restrict__ h, const float* __restrict__ hw,
    const float* __restrict__ hb, float* __restrict__ out, int n_nodes)
{
    int n = blockIdx.x;
    if (n >= n_nodes) return;
    int t = threadIdx.x;
    float h0 = h[(size_t)n*128 + t], h1 = h[(size_t)n*128 + 64 + t];
    float c0 = h0*hw[t*2]     + h1*hw[(t+64)*2];
    float c1 = h0*hw[t*2 + 1] + h1*hw[(t+64)*2 + 1];
    for (int off = 32; off > 0; off >>= 1) {
        c0 += __shfl_down(c0, off);
        c1 += __shfl_down(c1, off);
    }
    if (t == 0) {
        out[n*2]     = c0 + hb[0];
        out[n*2 + 1] = c1 + hb[1];
    }
}

extern "C" void kernel_launch(void* const* d_in, const int* in_sizes, int n_in,
                              void* d_out, int out_size, void* d_ws, size_t ws_size,
                              hipStream_t stream)
{
    const float* x      = (const float*)d_in[0];
    const int*   ef     = (const int*)d_in[1];
    const int*   er     = (const int*)d_in[2];
    const float* in_w   = (const float*)d_in[3];
    const float* in_b   = (const float*)d_in[4];
    const float* kqv_w  = (const float*)d_in[5];
    const float* kqv_b  = (const float*)d_in[6];
    const float* krel_w = (const float*)d_in[7];
    const float* vrel_w = (const float*)d_in[8];
    const float* p_rel  = (const float*)d_in[9];
    const float* out_w  = (const float*)d_in[10];
    const float* out_b  = (const float*)d_in[11];
    const float* skip   = (const float*)d_in[12];
    const float* head_w = (const float*)d_in[13];
    const float* head_b = (const float*)d_in[14];
    float* out = (float*)d_out;

    int n_nodes = in_sizes[0] / 128;
    int Ef = in_sizes[1] / 2, Er = in_sizes[2] / 2;
    int Etot = Ef + Er;
    int nch = (n_nodes + 255)/256;

    // workspace
    float* p = (float*)d_ws;
    float* h    = p; p += (size_t)n_nodes*128;
    float* qa   = p; p += (size_t)n_nodes*128;
    unsigned* kv = (unsigned*)p; p += (size_t)2*n_nodes*128;   // bf16 k|v packed
    float* Wc   = p; p += (size_t)2*129*640;
    int* deg       = (int*)p;      p += n_nodes;
    int* csum      = (int*)p;      p += 1024;
    int* row_start = (int*)p;      p += n_nodes + 1;
    int* cursor    = (int*)p;      p += n_nodes + 1;
    unsigned* srcs = (unsigned*)p; p += Etot;

    int ntile = (n_nodes + 63)/64;

    // ---- CSR build + weight compose ----
    k_zero_i<<<(n_nodes + 255)/256, 256, 0, stream>>>(deg, n_nodes);
    k_count<<<1024, 256, 0, stream>>>(ef, er, deg, Ef, Er);
    k_chunk_sums<<<nch, 256, 0, stream>>>(deg, csum, n_nodes);
    k_scan_chunks<<<1, 1024, 0, stream>>>(csum, nch);
    k_rowstart<<<(n_nodes + 256)/256, 256, 0, stream>>>(deg, csum, row_start, cursor, n_nodes);
    k_fill<<<1024, 256, 0, stream>>>(ef, er, cursor, srcs, Ef, Er);
    k_compose<<<(2*129*640 + 255)/256, 256, 0, stream>>>(kqv_w, kqv_b, krel_w, vrel_w,
                                                         p_rel, Wc);

    // ---- network ----
    k_gemm<<<ntile*2, 256, 0, stream>>>(x, in_w, 128, in_b, h,
                                        nullptr, skip, 0, n_nodes, 2, 0);
    for (int l = 0; l < 2; ++l) {
        const float* Wl = Wc + (size_t)l*129*640;
        k_gemm<<<ntile*10, 256, 0, stream>>>(h, Wl, 640, Wl + 128*640, qa,
                                             kv, skip, l, n_nodes, 10, 1);
        k_attn<<<(n_nodes + 7)/8, 256, 0, stream>>>(srcs, row_start,
                                                    (const uint4*)kv, qa, n_nodes);
        k_gemm<<<ntile*2, 256, 0, stream>>>(qa, out_w + (size_t)l*128*128, 128,
                                            out_b + (size_t)l*128, h,
                                            nullptr, skip, l, n_nodes, 2, 2);
    }
    k_head<<<n_nodes, 64, 0, stream>>>(h, head_w, head_b, out, n_nodes);
}

// Round 9
// 659.294 us; speedup vs baseline: 3.2980x; 1.0509x over previous
//
#include <hip/hip_runtime.h>
#include <math.h>

// ---------------- helpers ----------------
__device__ __forceinline__ unsigned short f2bf(float f){   // RTN bf16
    unsigned u = __float_as_uint(f);
    unsigned r = u + 0x7fffu + ((u >> 16) & 1u);
    return (unsigned short)(r >> 16);
}

// ---------------- CSR build ----------------
__global__ void k_zero_i(int* __restrict__ p, int n)
{
    for (int i = blockIdx.x*blockDim.x + threadIdx.x; i < n; i += gridDim.x*blockDim.x)
        p[i] = 0;
}

__global__ void k_count(const int* __restrict__ ef, const int* __restrict__ er,
                        int* __restrict__ deg, int Ef, int Er)
{
    int Etot = Ef + Er;
    for (int e = blockIdx.x*blockDim.x + threadIdx.x; e < Etot; e += gridDim.x*blockDim.x) {
        int dst = (e < Ef) ? ef[Ef + e] : er[Er + (e - Ef)];
        atomicAdd(&deg[dst], 1);
    }
}

__global__ void k_chunk_sums(const int* __restrict__ deg, int* __restrict__ csum, int n)
{
    __shared__ int s[256];
    int t = threadIdx.x, i = blockIdx.x*256 + t;
    s[t] = (i < n) ? deg[i] : 0;
    __syncthreads();
    for (int off = 128; off > 0; off >>= 1) {
        if (t < off) s[t] += s[t + off];
        __syncthreads();
    }
    if (t == 0) csum[blockIdx.x] = s[0];
}

__global__ void k_scan_chunks(int* __restrict__ csum, int nch)
{
    __shared__ int s[1024];
    int t = threadIdx.x;
    int v = (t < nch) ? csum[t] : 0;
    s[t] = v; __syncthreads();
    for (int off = 1; off < 1024; off <<= 1) {
        int u = (t >= off) ? s[t - off] : 0;
        __syncthreads();
        s[t] += u;
        __syncthreads();
    }
    if (t < nch) csum[t] = s[t] - v;
}

__global__ void k_rowstart(const int* __restrict__ deg, const int* __restrict__ csum,
                           int* __restrict__ row_start, int* __restrict__ cursor, int n)
{
    __shared__ int s[256];
    int t = threadIdx.x, i = blockIdx.x*256 + t;
    int d = (i < n) ? deg[i] : 0;
    s[t] = d; __syncthreads();
    for (int off = 1; off < 256; off <<= 1) {
        int u = (t >= off) ? s[t - off] : 0;
        __syncthreads();
        s[t] += u;
        __syncthreads();
    }
    if (i <= n) {
        int rs = csum[blockIdx.x] + s[t] - d;   // exclusive
        row_start[i] = rs;
        cursor[i] = rs;
    }
}

__global__ void k_fill(const int* __restrict__ ef, const int* __restrict__ er,
                       int* __restrict__ cursor, unsigned* __restrict__ srcs,
                       int Ef, int Er)
{
    int Etot = Ef + Er;
    for (int e = blockIdx.x*blockDim.x + threadIdx.x; e < Etot; e += gridDim.x*blockDim.x) {
        int src, dst; unsigned tbit;
        if (e < Ef) { src = ef[e]; dst = ef[Ef + e]; tbit = 0u; }
        else { int e2 = e - Ef; src = er[e2]; dst = er[Er + e2]; tbit = 0x80000000u; }
        int pos = atomicAdd(&cursor[dst], 1);
        srcs[pos] = (unsigned)src | tbit;
    }
}

// ---------------- composed weights ----------------
// Wc[l] 129 x 640 (row 128 = bias):
//   cols   0-127: q
//   cols 128-639: per edge type tt (256 cols each), INTERLEAVED per feature:
//     col 128 + tt*256 + 2f   = krel feature f (p*scale folded)
//     col 128 + tt*256 + 2f+1 = vrel feature f
__global__ void k_compose(const float* __restrict__ kqv_w, const float* __restrict__ kqv_b,
                          const float* __restrict__ krel_w, const float* __restrict__ vrel_w,
                          const float* __restrict__ p_rel, float* __restrict__ Wc)
{
    int idx = blockIdx.x*blockDim.x + threadIdx.x;
    int tot = 2*129*640;
    if (idx >= tot) return;
    int l = idx / (129*640);
    int rem = idx % (129*640);
    int r = rem / 640, c = rem % 640;
    float val;
    if (c < 128) {
        val = (r < 128) ? kqv_w[((size_t)l*128 + r)*384 + 128 + c]
                        : kqv_b[l*384 + 128 + c];
    } else {
        int c2 = c - 128;
        int tt = c2 >> 8;
        int cc = c2 & 255;
        int f = cc >> 1;
        int part = cc & 1;             // 0 = k, 1 = v
        int hh = f >> 4, fd = f & 15;
        const float* rw = (part == 0 ? krel_w : vrel_w)
                          + (((size_t)(l*2 + tt)*8 + hh)*16)*16 + fd;
        int base_col = (part == 0 ? 0 : 256) + hh*16;
        float s = 0.f;
        #pragma unroll
        for (int d = 0; d < 16; ++d) {
            float a = (r < 128) ? kqv_w[((size_t)l*128 + r)*384 + base_col + d]
                                : kqv_b[l*384 + base_col + d];
            s += a * rw[d*16];
        }
        if (part == 0) s *= p_rel[(l*2 + tt)*8 + hh] * 0.25f;
        val = s;
    }
    Wc[idx] = val;
}

// ---------------- tiled GEMM ----------------
// BM=64, BN=64, BK=32; 256 threads; 4x4 register tile.
// As_t stored transposed with XOR swizzle: element (r,m) at col m ^ ((r>>2)<<3)
//   -> staging writes 2-way (free), inner reads aligned float4 broadcasts.
// mode 0: plain f32 store; mode 1: q->f32, interleaved kv tiles -> packed uint kv words;
// mode 2: h = relu(g*C + (1-g)*h)
__global__ __launch_bounds__(256) void k_gemm(
    const float* __restrict__ A, const float* __restrict__ W, int ldw,
    const float* __restrict__ bias, float* __restrict__ out0,
    unsigned* __restrict__ kv, const float* __restrict__ skip, int l,
    int n_nodes, int ncol_tiles, int mode)
{
    __shared__ float As_t[32][64];
    __shared__ float Ws[32][64];
    int tile_n = blockIdx.x / ncol_tiles;
    int tile_c = blockIdx.x % ncol_tiles;
    int n0 = tile_n*64, c0 = tile_c*64;
    int t = threadIdx.x, tx = t & 15, ty = t >> 4;

    float4 b4 = *(const float4*)&bias[c0 + tx*4];
    float acc[4][4];
    #pragma unroll
    for (int r = 0; r < 4; ++r) {
        acc[r][0] = b4.x; acc[r][1] = b4.y; acc[r][2] = b4.z; acc[r][3] = b4.w;
    }

    for (int kk = 0; kk < 128; kk += 32) {
        __syncthreads();
        #pragma unroll
        for (int it = 0; it < 2; ++it) {
            int idx = t + it*256;          // [0,512)
            int m = idx >> 3, c4 = idx & 7;
            int n = n0 + m;
            float4 a = make_float4(0.f, 0.f, 0.f, 0.f);
            if (n < n_nodes) a = *(const float4*)&A[(size_t)n*128 + kk + c4*4];
            int col = m ^ (c4 << 3);       // swizzle: (r>>2)==c4 for all 4 rows
            As_t[c4*4 + 0][col] = a.x;
            As_t[c4*4 + 1][col] = a.y;
            As_t[c4*4 + 2][col] = a.z;
            As_t[c4*4 + 3][col] = a.w;
        }
        #pragma unroll
        for (int it = 0; it < 2; ++it) {
            int idx = t + it*256;
            int r = idx >> 4, c4 = idx & 15;
            *(float4*)&Ws[r][c4*4] = *(const float4*)&W[(size_t)(kk + r)*ldw + c0 + c4*4];
        }
        __syncthreads();
        #pragma unroll 8
        for (int k = 0; k < 32; ++k) {
            float4 a = *(const float4*)&As_t[k][(ty*4) ^ ((k >> 2) << 3)];
            float4 w = *(const float4*)&Ws[k][tx*4];
            acc[0][0] += a.x*w.x; acc[0][1] += a.x*w.y; acc[0][2] += a.x*w.z; acc[0][3] += a.x*w.w;
            acc[1][0] += a.y*w.x; acc[1][1] += a.y*w.y; acc[1][2] += a.y*w.z; acc[1][3] += a.y*w.w;
            acc[2][0] += a.z*w.x; acc[2][1] += a.z*w.y; acc[2][2] += a.z*w.z; acc[2][3] += a.z*w.w;
            acc[3][0] += a.w*w.x; acc[3][1] += a.w*w.y; acc[3][2] += a.w*w.z; acc[3][3] += a.w*w.w;
        }
    }

    if (mode == 1 && c0 >= 128) {
        // interleaved tile: acc cols = [k_f0, v_f0, k_f1, v_f1]; pack full words.
        int c2 = c0 - 128;
        int tt = c2 >> 8;
        int fbase = ((c2 & 255) >> 1) + tx*2;
        unsigned* dst = kv + (size_t)tt*n_nodes*128;
        #pragma unroll
        for (int r = 0; r < 4; ++r) {
            int n = n0 + ty*4 + r;
            if (n >= n_nodes) break;
            uint2 w;
            w.x = ((unsigned)f2bf(acc[r][0]) << 16) | (unsigned)f2bf(acc[r][1]);
            w.y = ((unsigned)f2bf(acc[r][2]) << 16) | (unsigned)f2bf(acc[r][3]);
            *(uint2*)&dst[(size_t)n*128 + fbase] = w;
        }
    } else if (mode == 2) {
        float g = 1.f/(1.f + expf(-skip[l]));
        #pragma unroll
        for (int r = 0; r < 4; ++r) {
            int n = n0 + ty*4 + r;
            if (n >= n_nodes) break;
            float4 hv = *(const float4*)&out0[(size_t)n*128 + c0 + tx*4];
            float4 o;
            o.x = fmaxf(g*acc[r][0] + (1.f - g)*hv.x, 0.f);
            o.y = fmaxf(g*acc[r][1] + (1.f - g)*hv.y, 0.f);
            o.z = fmaxf(g*acc[r][2] + (1.f - g)*hv.z, 0.f);
            o.w = fmaxf(g*acc[r][3] + (1.f - g)*hv.w, 0.f);
            *(float4*)&out0[(size_t)n*128 + c0 + tx*4] = o;
        }
    } else {
        #pragma unroll
        for (int r = 0; r < 4; ++r) {
            int n = n0 + ty*4 + r;
            if (n >= n_nodes) break;
            float4 o = make_float4(acc[r][0], acc[r][1], acc[r][2], acc[r][3]);
            *(float4*)&out0[(size_t)n*128 + c0 + tx*4] = o;
        }
    }
}

// ---------------- fused gather attention ----------------
// 32 lanes per node (8 nodes / 256-thr block), 4 features/lane (uint4 kv load),
// online softmax (p*scale folded into k), gelu epilogue. qa in/out.
__global__ __launch_bounds__(256) void k_attn(
    const unsigned* __restrict__ srcs, const int* __restrict__ row_start,
    const uint4* __restrict__ kv, float* __restrict__ qa, int n_nodes)
{
    int lane = threadIdx.x & 31;
    int n = blockIdx.x*8 + (threadIdx.x >> 5);
    if (n >= n_nodes) return;
    float4 q4 = *(const float4*)&qa[(size_t)n*128 + lane*4];
    int s = row_start[n], e = row_start[n + 1];
    float m = -INFINITY, lsum = 0.f;
    float4 acc = make_float4(0.f, 0.f, 0.f, 0.f);

    uint4 w4n;
    if (s < e) {
        unsigned sv = srcs[s];
        w4n = kv[(((size_t)(sv >> 31))*n_nodes + (sv & 0x7fffffffu))*32 + lane];
    }
    for (int pos = s; pos < e; ) {
        uint4 w4 = w4n;
        ++pos;
        if (pos < e) {
            unsigned sv = srcs[pos];
            w4n = kv[(((size_t)(sv >> 31))*n_nodes + (sv & 0x7fffffffu))*32 + lane];
        }
        float d = __uint_as_float(w4.x & 0xffff0000u)*q4.x
                + __uint_as_float(w4.y & 0xffff0000u)*q4.y
                + __uint_as_float(w4.z & 0xffff0000u)*q4.z
                + __uint_as_float(w4.w & 0xffff0000u)*q4.w;
        d += __shfl_xor(d, 1);
        d += __shfl_xor(d, 2);
        float mn = fmaxf(m, d);
        float sc = __expf(m - mn);
        float w  = __expf(d - mn);
        lsum = lsum*sc + w;
        acc.x = acc.x*sc + w*__uint_as_float(w4.x << 16);
        acc.y = acc.y*sc + w*__uint_as_float(w4.y << 16);
        acc.z = acc.z*sc + w*__uint_as_float(w4.z << 16);
        acc.w = acc.w*sc + w*__uint_as_float(w4.w << 16);
        m = mn;
    }
    float inv = 1.f/(lsum + 1e-16f);
    float4 o;
    float x0 = acc.x*inv, x1 = acc.y*inv, x2 = acc.z*inv, x3 = acc.w*inv;
    o.x = 0.5f*x0*(1.f + erff(x0*0.70710678118654752f));
    o.y = 0.5f*x1*(1.f + erff(x1*0.70710678118654752f));
    o.z = 0.5f*x2*(1.f + erff(x2*0.70710678118654752f));
    o.w = 0.5f*x3*(1.f + erff(x3*0.70710678118654752f));
    *(float4*)&qa[(size_t)n*128 + lane*4] = o;
}

// head: one wave per node, shuffle reduce
__global__ __launch_bounds__(64) void k_head(
    const float* __restrict__ h, const float* __restrict__ hw,
    const float* __restrict__ hb, float* __restrict__ out, int n_nodes)
{
    int n = blockIdx.x;
    if (n >= n_nodes) return;
    int t = threadIdx.x;
    float h0 = h[(size_t)n*128 + t], h1 = h[(size_t)n*128 + 64 + t];
    float c0 = h0*hw[t*2]     + h1*hw[(t+64)*2];
    float c1 = h0*hw[t*2 + 1] + h1*hw[(t+64)*2 + 1];
    for (int off = 32; off > 0; off >>= 1) {
        c0 += __shfl_down(c0, off);
        c1 += __shfl_down(c1, off);
    }
    if (t == 0) {
        out[n*2]     = c0 + hb[0];
        out[n*2 + 1] = c1 + hb[1];
    }
}

extern "C" void kernel_launch(void* const* d_in, const int* in_sizes, int n_in,
                              void* d_out, int out_size, void* d_ws, size_t ws_size,
                              hipStream_t stream)
{
    const float* x      = (const float*)d_in[0];
    const int*   ef     = (const int*)d_in[1];
    const int*   er     = (const int*)d_in[2];
    const float* in_w   = (const float*)d_in[3];
    const float* in_b   = (const float*)d_in[4];
    const float* kqv_w  = (const float*)d_in[5];
    const float* kqv_b  = (const float*)d_in[6];
    const float* krel_w = (const float*)d_in[7];
    const float* vrel_w = (const float*)d_in[8];
    const float* p_rel  = (const float*)d_in[9];
    const float* out_w  = (const float*)d_in[10];
    const float* out_b  = (const float*)d_in[11];
    const float* skip   = (const float*)d_in[12];
    const float* head_w = (const float*)d_in[13];
    const float* head_b = (const float*)d_in[14];
    float* out = (float*)d_out;

    int n_nodes = in_sizes[0] / 128;
    int Ef = in_sizes[1] / 2, Er = in_sizes[2] / 2;
    int Etot = Ef + Er;
    int nch = (n_nodes + 255)/256;

    // workspace
    float* p = (float*)d_ws;
    float* h    = p; p += (size_t)n_nodes*128;
    float* qa   = p; p += (size_t)n_nodes*128;
    unsigned* kv = (unsigned*)p; p += (size_t)2*n_nodes*128;   // packed bf16 (k<<16)|v
    float* Wc   = p; p += (size_t)2*129*640;
    int* deg       = (int*)p;      p += n_nodes;
    int* csum      = (int*)p;      p += 1024;
    int* row_start = (int*)p;      p += n_nodes + 1;
    int* cursor    = (int*)p;      p += n_nodes + 1;
    unsigned* srcs = (unsigned*)p; p += Etot;

    int ntile = (n_nodes + 63)/64;

    // ---- CSR build + weight compose ----
    k_zero_i<<<(n_nodes + 255)/256, 256, 0, stream>>>(deg, n_nodes);
    k_count<<<1024, 256, 0, stream>>>(ef, er, deg, Ef, Er);
    k_chunk_sums<<<nch, 256, 0, stream>>>(deg, csum, n_nodes);
    k_scan_chunks<<<1, 1024, 0, stream>>>(csum, nch);
    k_rowstart<<<(n_nodes + 256)/256, 256, 0, stream>>>(deg, csum, row_start, cursor, n_nodes);
    k_fill<<<1024, 256, 0, stream>>>(ef, er, cursor, srcs, Ef, Er);
    k_compose<<<(2*129*640 + 255)/256, 256, 0, stream>>>(kqv_w, kqv_b, krel_w, vrel_w,
                                                         p_rel, Wc);

    // ---- network ----
    k_gemm<<<ntile*2, 256, 0, stream>>>(x, in_w, 128, in_b, h,
                                        nullptr, skip, 0, n_nodes, 2, 0);
    for (int l = 0; l < 2; ++l) {
        const float* Wl = Wc + (size_t)l*129*640;
        k_gemm<<<ntile*10, 256, 0, stream>>>(h, Wl, 640, Wl + 128*640, qa,
                                             kv, skip, l, n_nodes, 10, 1);
        k_attn<<<(n_nodes + 7)/8, 256, 0, stream>>>(srcs, row_start,
                                                    (const uint4*)kv, qa, n_nodes);
        k_gemm<<<ntile*2, 256, 0, stream>>>(qa, out_w + (size_t)l*128*128, 128,
                                            out_b + (size_t)l*128, h,
                                            nullptr, skip, l, n_nodes, 2, 2);
    }
    k_head<<<n_nodes, 64, 0, stream>>>(h, head_w, head_b, out, n_nodes);
}